// Round 10
// baseline (2270.478 us; speedup 1.0000x reference)
//
#include <hip/hip_runtime.h>

#define DIMV 768
#define BATCH 16
#define SEQ 1024
#define LN_EPS 1e-5f

typedef __attribute__((ext_vector_type(8))) short bf16x8;   // 8 bf16 = 4 VGPRs
typedef __attribute__((ext_vector_type(4))) float f32x4;
typedef unsigned short ushort_t;

__device__ __forceinline__ unsigned short f2bf(float f) {
    unsigned u = __float_as_uint(f);
    u = (u + 0x7FFFu + ((u >> 16) & 1u)) >> 16;
    return (unsigned short)u;
}

// ---------------------------------------------------------------------------
// Verified building blocks (rounds 0-9):
//  - LDS chunk swizzle on global SOURCE + frag-read XOR (conflicts -> 0).
//  - XCD swizzles: Z>1 -> XCD == batch (mod 8); Z==1 -> chunked y-range.
//  - Branch-fused attention; lifetime overlays -> single chunk Cb=16.
// GEMM structure ledger (pre-committed A/B outcomes, all ~466-480 TF):
//  r4 depth-2@128^2 REFUTED (occupancy), r6 256^2@1blk +6.6%, r7 depth-2
//  iso-occ NULL, r8 BK=64 ring-2 NULL, r9 8-phase NULL. Only axis that ever
//  moved per-family throughput: resident blocks/CU (TLP). THIS ROUND:
//  256^2 tile at TWO blocks/CU (BK=32 ring-2 two-barrier, 64 KB LDS).
// ---------------------------------------------------------------------------

// ---------------------------------------------------------------------------
// 256x256 tile GEMM, BK=32, ring-2 double-buffer (64 KB) -> 2 blocks/CU,
// counted vmcnt(4), two barriers/iter:
//   iter k: issue(k+1 -> slot (k+1)&1); vmcnt(4); barrier_a;
//           ds_read 12 frags from slot k&1; 32 MFMA (setprio 1/0);
//           lgkmcnt(0); barrier_b
// Safety:
//  - barrier_a: every wave waited its OWN vmcnt(4) (= its share of tile k)
//    -> after barrier_a all tile-k staging is complete; the 4 newest loads
//    (tile k+1) stay in flight across the barrier (T4: never drain to 0).
//  - barrier_b: ds_reads of slot k&1 are DRAINED (explicit lgkmcnt(0),
//    rule #18) before any wave crosses; iter-(k+1)'s issue targets slot
//    (k+2)&1 = k&1 and executes after barrier_b(k) -> no overwrite race.
//  - last iter issues a clamped dummy (last tile, L2-hot; its slot's readers
//    drained at barrier_b(NK-2)) so the vmcnt count stays uniform.
// Occupancy: 64 KB LDS + <=128 VGPR -> 2 blocks/CU (16 waves/CU): while one
// block's waves sit in vmcnt/barrier, the co-resident block feeds the MFMA
// pipe (the TLP mechanism measured at 128^2@3blocks).
// mode: 0 = f32 out; 1 = bf16 out; 4 = fused KV epilogue (branch-stacked):
//           bh = m>>10, half = bh>=CbArg, b = bh - half*CbArg
//           n < 768 : K  -> Cout [b][half*1024 + s][n]       (bf16)
//           n >= 768: V^T-> Cout2[b][n-768][half*1024 + s]   (bf16)
// ---------------------------------------------------------------------------
__global__ __launch_bounds__(512, 4) void gemm_bf16_nt_256(
    const ushort_t* __restrict__ A, const ushort_t* __restrict__ B,
    const float* __restrict__ bias, const float* __restrict__ bias2,
    void* __restrict__ Cout, void* __restrict__ Cout2,
    int K, int lda, int ldb, int ldc, float scale, int mode,
    long long sAz, long long sBz, long long sCz, int CbArg)
{
    int bx = blockIdx.x, by = blockIdx.y, bz = blockIdx.z;
    {
        const unsigned Z  = gridDim.z;
        const unsigned nx = gridDim.x, ny = gridDim.y;
        if (Z > 1) {
            const unsigned nxy = nx * ny;
            const unsigned lid = ((unsigned)bz * ny + (unsigned)by) * nx + (unsigned)bx;
            unsigned r;
            if ((Z & 7u) == 0u) {
                const unsigned c  = lid & 7u;
                const unsigned rp = lid >> 3;
                bz = (int)(c + 8u * (rp / nxy));
                r  = rp % nxy;
            } else {
                bz = (int)(lid % Z);
                r  = lid / Z;
            }
            bx = (int)(r % nx);
            by = (int)(r / nx);
        } else {
            const unsigned nwg = nx * ny;
            if ((nwg & 7u) == 0u) {
                const unsigned lid = (unsigned)by * nx + (unsigned)bx;
                const unsigned nl  = (lid & 7u) * (nwg >> 3) + (lid >> 3);
                bx = (int)(nl % nx);
                by = (int)(nl / nx);
            }
        }
    }

    A += (long long)bz * sAz;
    B += (long long)bz * sBz;
    float*    Cf  = (float*)Cout    + ((mode == 0) ? (long long)bz * sCz : 0);
    ushort_t* Ch  = (ushort_t*)Cout + ((mode == 1) ? (long long)bz * sCz : 0);
    ushort_t* Ch2 = (ushort_t*)Cout2;

    __shared__ ushort_t As[2][256 * 32];   // 2 x 16 KB
    __shared__ ushort_t Bs[2][256 * 32];   // 2 x 16 KB  (64 KB total)

    const int t    = threadIdx.x;       // 0..511
    const int wave = t >> 6;            // 0..7
    const int lane = t & 63;
    const int quad = lane >> 4;         // 0..3
    const int lr   = lane & 15;         // 0..15
    const int wy   = wave >> 2;         // 0/1: m-half (128 rows)
    const int wx   = wave & 3;          // 0..3: n-quarter (64 cols)

    const int m0 = by * 256;
    const int n0 = bx * 256;

    const ushort_t* Abase = A + (long long)m0 * lda;
    const ushort_t* Bbase = B + (long long)n0 * ldb;

    auto issue = [&](int k0, int slot) {
        #pragma unroll
        for (int i = 0; i < 2; ++i) {
            const int idx = t + 512 * i;          // 0..1023: 256 rows x 4 chunks
            const int r   = idx >> 2;
            const int q   = idx & 3;              // LDS chunk slot
            const int c   = (q ^ ((r >> 1) & 3)) * 8;  // swizzled global chunk
            __builtin_amdgcn_global_load_lds(
                (const __attribute__((address_space(1))) unsigned int*)(Abase + (long long)r * lda + k0 + c),
                (__attribute__((address_space(3))) unsigned int*)&As[slot][idx * 8], 16, 0, 0);
            __builtin_amdgcn_global_load_lds(
                (const __attribute__((address_space(1))) unsigned int*)(Bbase + (long long)r * ldb + k0 + c),
                (__attribute__((address_space(3))) unsigned int*)&Bs[slot][idx * 8], 16, 0, 0);
        }
    };

    // Swizzled frag-read offsets (loop-invariant): row's global chunk `quad`
    // lives at LDS slot quad ^ ((row>>1)&3).  [verified: conflicts -> 0]
    int offA[8], offB[4];
    #pragma unroll
    for (int i = 0; i < 8; ++i) {
        const int rowA = wy * 128 + i * 16 + lr;
        offA[i] = rowA * 32 + ((quad ^ ((rowA >> 1) & 3)) * 8);
    }
    #pragma unroll
    for (int j = 0; j < 4; ++j) {
        const int rowB = wx * 64 + j * 16 + lr;
        offB[j] = rowB * 32 + ((quad ^ ((rowB >> 1) & 3)) * 8);
    }

    f32x4 acc[8][4] = {};

    const int NK = K >> 5;                 // K=768 -> 24
    issue(0, 0);
    for (int ki = 0; ki < NK; ++ki) {
        const int kn = (ki + 1 < NK) ? (ki + 1) << 5 : (NK - 1) << 5;  // clamped dummy
        issue(kn, (ki + 1) & 1);
        asm volatile("s_waitcnt vmcnt(4)" ::: "memory");   // tile k staged; k+1 in flight
        asm volatile("s_barrier" ::: "memory");            // barrier_a

        const ushort_t* as = &As[ki & 1][0];
        const ushort_t* bs = &Bs[ki & 1][0];
        bf16x8 af[8], bfr[4];
        #pragma unroll
        for (int i = 0; i < 8; ++i) af[i]  = *(const bf16x8*)&as[offA[i]];
        #pragma unroll
        for (int j = 0; j < 4; ++j) bfr[j] = *(const bf16x8*)&bs[offB[j]];

        __builtin_amdgcn_s_setprio(1);
        #pragma unroll
        for (int i = 0; i < 8; ++i)
            #pragma unroll
            for (int j = 0; j < 4; ++j)
                acc[i][j] = __builtin_amdgcn_mfma_f32_16x16x32_bf16(
                    af[i], bfr[j], acc[i][j], 0, 0, 0);
        __builtin_amdgcn_s_setprio(0);

        asm volatile("s_waitcnt lgkmcnt(0)" ::: "memory"); // reads drained (rule #18)
        asm volatile("s_barrier" ::: "memory");            // barrier_b
    }

    // epilogue: D row(m) = quad*4 + reg, col(n) = lane&15  [m89-verified]
    #pragma unroll
    for (int j = 0; j < 4; ++j) {
        const int n = n0 + wx * 64 + j * 16 + lr;
        float bv;
        if (mode == 4) bv = (n < DIMV) ? bias[n] : bias2[n - DIMV];
        else           bv = bias ? bias[n] : 0.0f;
        #pragma unroll
        for (int i = 0; i < 8; ++i) {
            #pragma unroll
            for (int r = 0; r < 4; ++r) {
                const int m = m0 + wy * 128 + i * 16 + quad * 4 + r;
                const float val = acc[i][j][r] * scale + bv;
                if (mode == 0) {
                    Cf[(long long)m * ldc + n] = val;
                } else if (mode == 1) {
                    Ch[(long long)m * ldc + n] = f2bf(val);
                } else {                      // mode 4: fused KV, branch-stacked
                    const int bh = m >> 10, s = m & 1023;
                    const int hf = (bh >= CbArg) ? 1 : 0;
                    const int b  = bh - (hf ? CbArg : 0);
                    if (n < DIMV) {
                        Ch[(long long)b * (2 * SEQ * DIMV) + (long long)(hf * SEQ + s) * DIMV + n] = f2bf(val);
                    } else {
                        Ch2[(long long)b * (2 * SEQ * DIMV) + (long long)(n - DIMV) * (2 * SEQ) + hf * SEQ + s] = f2bf(val);
                    }
                }
            }
        }
    }
}

// ---------------------------------------------------------------------------
// 128x128 tile GEMM, BK=32 ring-3 depth-1 (verified rounds 0-5) — kept for
// PV, whose per-batch grid underfills the chip at 256^2 tiles. mode 0 only.
// ---------------------------------------------------------------------------
__global__ __launch_bounds__(256) void gemm_bf16_nt(
    const ushort_t* __restrict__ A, const ushort_t* __restrict__ B,
    const float* __restrict__ bias, void* __restrict__ Cout,
    int K, int lda, int ldb, int ldc, float scale,
    long long sAz, long long sBz, long long sCz)
{
    int bx = blockIdx.x, by = blockIdx.y, bz = blockIdx.z;
    {
        const unsigned Z  = gridDim.z;
        const unsigned nx = gridDim.x, ny = gridDim.y;
        if (Z > 1) {
            const unsigned nxy = nx * ny;
            const unsigned lid = ((unsigned)bz * ny + (unsigned)by) * nx + (unsigned)bx;
            unsigned r;
            if ((Z & 7u) == 0u) {
                const unsigned c  = lid & 7u;
                const unsigned rp = lid >> 3;
                bz = (int)(c + 8u * (rp / nxy));
                r  = rp % nxy;
            } else {
                bz = (int)(lid % Z);
                r  = lid / Z;
            }
            bx = (int)(r % nx);
            by = (int)(r / nx);
        } else {
            const unsigned nwg = nx * ny;
            if ((nwg & 7u) == 0u) {
                const unsigned lid = (unsigned)by * nx + (unsigned)bx;
                const unsigned nl  = (lid & 7u) * (nwg >> 3) + (lid >> 3);
                bx = (int)(nl % nx);
                by = (int)(nl / nx);
            }
        }
    }

    A += (long long)bz * sAz;
    B += (long long)bz * sBz;
    float* Cf = (float*)Cout + (long long)bz * sCz;

    __shared__ ushort_t As[3][128 * 32];
    __shared__ ushort_t Bs[3][128 * 32];

    const int t    = threadIdx.x;
    const int wave = t >> 6;
    const int lane = t & 63;
    const int quad = lane >> 4;
    const int lr   = lane & 15;
    const int wy   = wave >> 1;
    const int wx   = wave & 1;

    const int m0 = by * 128;
    const int n0 = bx * 128;

    const ushort_t* Abase = A + (long long)m0 * lda;
    const ushort_t* Bbase = B + (long long)n0 * ldb;

    auto issue = [&](int k0, int slot) {
        #pragma unroll
        for (int i = 0; i < 2; ++i) {
            const int idx = t + 256 * i;
            const int r   = idx >> 2;
            const int q   = idx & 3;
            const int c   = (q ^ ((r >> 1) & 3)) * 8;
            __builtin_amdgcn_global_load_lds(
                (const __attribute__((address_space(1))) unsigned int*)(Abase + (long long)r * lda + k0 + c),
                (__attribute__((address_space(3))) unsigned int*)&As[slot][idx * 8], 16, 0, 0);
            __builtin_amdgcn_global_load_lds(
                (const __attribute__((address_space(1))) unsigned int*)(Bbase + (long long)r * ldb + k0 + c),
                (__attribute__((address_space(3))) unsigned int*)&Bs[slot][idx * 8], 16, 0, 0);
        }
    };

    int offA[4], offB[4];
    #pragma unroll
    for (int i = 0; i < 4; ++i) {
        const int rowA = wy * 64 + i * 16 + lr;
        offA[i] = rowA * 32 + ((quad ^ ((rowA >> 1) & 3)) * 8);
        const int rowB = wx * 64 + i * 16 + lr;
        offB[i] = rowB * 32 + ((quad ^ ((rowB >> 1) & 3)) * 8);
    }

    f32x4 acc[4][4] = {};

    const int NK = K >> 5;
    issue(0, 0);
    int cur = 0, nxt = 1;
    for (int ki = 0; ki < NK; ++ki) {
        const int kn = (ki + 1 < NK) ? (ki + 1) << 5 : 0;
        issue(kn, nxt);
        asm volatile("s_waitcnt vmcnt(4)" ::: "memory");
        asm volatile("s_barrier" ::: "memory");

        const ushort_t* as = &As[cur][0];
        const ushort_t* bs = &Bs[cur][0];
        bf16x8 af[4], bfr[4];
        #pragma unroll
        for (int i = 0; i < 4; ++i) af[i]  = *(const bf16x8*)&as[offA[i]];
        #pragma unroll
        for (int j = 0; j < 4; ++j) bfr[j] = *(const bf16x8*)&bs[offB[j]];

        #pragma unroll
        for (int i = 0; i < 4; ++i)
            #pragma unroll
            for (int j = 0; j < 4; ++j)
                acc[i][j] = __builtin_amdgcn_mfma_f32_16x16x32_bf16(
                    af[i], bfr[j], acc[i][j], 0, 0, 0);

        cur = nxt;
        nxt = (nxt == 2) ? 0 : nxt + 1;
    }

    #pragma unroll
    for (int j = 0; j < 4; ++j) {
        const int n = n0 + wx * 64 + j * 16 + lr;
        const float bv = bias ? bias[n] : 0.0f;
        #pragma unroll
        for (int i = 0; i < 4; ++i) {
            #pragma unroll
            for (int r = 0; r < 4; ++r) {
                const int m = m0 + wy * 64 + i * 16 + quad * 4 + r;
                Cf[(long long)m * ldc + n] = acc[i][j][r] * scale + bv;
            }
        }
    }
}

// ---------------------------------------------------------------------------
// f32 -> bf16 conversion, 4 elems/thread, count divisible by 1024
// ---------------------------------------------------------------------------
__global__ __launch_bounds__(256) void f32_to_bf16(
    const float* __restrict__ in, ushort_t* __restrict__ out)
{
    const long long i = ((long long)blockIdx.x * 256 + threadIdx.x) * 4;
    float4 v = *reinterpret_cast<const float4*>(in + i);
    ushort4 o;
    o.x = f2bf(v.x); o.y = f2bf(v.y); o.z = f2bf(v.z); o.w = f2bf(v.w);
    *reinterpret_cast<ushort4*>(out + i) = o;
}

// ---------------------------------------------------------------------------
// Dual in-place row softmax over a [2048] f32 row (two independent 1024
// halves). Row overwritten with 2048 contiguous bf16 probs. [verified r4]
// ---------------------------------------------------------------------------
__global__ __launch_bounds__(256) void softmax2_inplace(float* __restrict__ S)
{
    float* s = S + (long long)blockIdx.x * (2 * SEQ);
    const int t  = threadIdx.x;
    const int hf = t >> 7;
    const int tt = t & 127;
    const int base = hf * SEQ + tt * 8;
    __shared__ float red[256];

    float4 v0 = *reinterpret_cast<const float4*>(&s[base]);
    float4 v1 = *reinterpret_cast<const float4*>(&s[base + 4]);
    float mx = fmaxf(fmaxf(fmaxf(v0.x, v0.y), fmaxf(v0.z, v0.w)),
                     fmaxf(fmaxf(v1.x, v1.y), fmaxf(v1.z, v1.w)));
    red[t] = mx;
    __syncthreads();
    for (int st = 64; st > 0; st >>= 1) {
        if (tt < st) red[t] = fmaxf(red[t], red[t + st]);
        __syncthreads();
    }
    mx = red[hf << 7];
    __syncthreads();

    v0.x = __expf(v0.x - mx); v0.y = __expf(v0.y - mx);
    v0.z = __expf(v0.z - mx); v0.w = __expf(v0.w - mx);
    v1.x = __expf(v1.x - mx); v1.y = __expf(v1.y - mx);
    v1.z = __expf(v1.z - mx); v1.w = __expf(v1.w - mx);
    red[t] = (v0.x + v0.y + v0.z + v0.w) + (v1.x + v1.y + v1.z + v1.w);
    __syncthreads();
    for (int st = 64; st > 0; st >>= 1) {
        if (tt < st) red[t] += red[t + st];
        __syncthreads();
    }
    const float inv = 1.0f / red[hf << 7];

    ushort4 o0, o1;
    o0.x = f2bf(v0.x * inv); o0.y = f2bf(v0.y * inv);
    o0.z = f2bf(v0.z * inv); o0.w = f2bf(v0.w * inv);
    o1.x = f2bf(v1.x * inv); o1.y = f2bf(v1.y * inv);
    o1.z = f2bf(v1.z * inv); o1.w = f2bf(v1.w * inv);
    *reinterpret_cast<ushort4*>((ushort_t*)s + base)     = o0;
    *reinterpret_cast<ushort4*>((ushort_t*)s + base + 4) = o1;
}

// ---------------------------------------------------------------------------
// h = LayerNorm(ACC + xC) * gamma + beta -> bf16. One block per row (768).
// ---------------------------------------------------------------------------
__global__ __launch_bounds__(256) void add_layernorm(
    const float* __restrict__ ACC, const float* __restrict__ xC,
    const float* __restrict__ gamma, const float* __restrict__ beta,
    ushort_t* __restrict__ H)
{
    const long long row = blockIdx.x;
    const float* a = ACC + row * DIMV;
    const float* x = xC  + row * DIMV;
    ushort_t*    h = H   + row * DIMV;
    const int t = threadIdx.x;

    __shared__ float r1[256];
    __shared__ float r2[256];

    float vals[3];
    float s = 0.f, ss = 0.f;
    #pragma unroll
    for (int i = 0; i < 3; ++i) {
        const int j = t + i * 256;
        float v = a[j] + x[j];
        vals[i] = v;
        s += v; ss += v * v;
    }
    r1[t] = s; r2[t] = ss;
    __syncthreads();
    for (int st = 128; st > 0; st >>= 1) {
        if (t < st) { r1[t] += r1[t + st]; r2[t] += r2[t + st]; }
        __syncthreads();
    }
    const float mu  = r1[0] * (1.0f / DIMV);
    const float var = r2[0] * (1.0f / DIMV) - mu * mu;
    const float inv = rsqrtf(var + LN_EPS);

    #pragma unroll
    for (int i = 0; i < 3; ++i) {
        const int j = t + i * 256;
        h[j] = f2bf((vals[i] - mu) * inv * gamma[j] + beta[j]);
    }
}

// ---------------------------------------------------------------------------
// Launch. Persistent: bf16 weights Wqb | Wkvb (=[Wk;Wv]) | Wfcb (4.72 MB).
// Lifetime-overlay layout per chunk [verified round 5, single chunk Cb=16]:
//   Region S: xCb / xABb / Sf (sequential lifetimes)
//   Qb; KbACC (Kb overlaid by ACC per sub-pass); Vtb
// Attention branch-fused per SC-batch sub-pass:
//   score (N=2048) -> dual softmax -> PV (K=2048, no RMW).
// 256^2 BK=32 ring-2 2-blocks/CU GEMM for Q/KV/score/fc; 128^2 ring-3 for PV.
// ---------------------------------------------------------------------------
extern "C" void kernel_launch(void* const* d_in, const int* in_sizes, int n_in,
                              void* d_out, int out_size, void* d_ws, size_t ws_size,
                              hipStream_t stream)
{
    const float* xA    = (const float*)d_in[0];
    const float* xB    = (const float*)d_in[1];
    const float* xC    = (const float*)d_in[2];
    const float* Wq    = (const float*)d_in[3];
    const float* bq    = (const float*)d_in[4];
    const float* Wk    = (const float*)d_in[5];
    const float* bk    = (const float*)d_in[6];
    const float* Wv    = (const float*)d_in[7];
    const float* bv    = (const float*)d_in[8];
    const float* gamma = (const float*)d_in[9];
    const float* beta  = (const float*)d_in[10];
    const float* Wfc   = (const float*)d_in[11];
    const float* bfc   = (const float*)d_in[12];
    float* out = (float*)d_out;

    const long long eW   = (long long)DIMV * DIMV;   // 589,824
    const long long perB = (long long)SEQ * DIMV;    // 786,432 elems
    const long long perP = (long long)SEQ * SEQ;     // 1,048,576 elems

    const long long wBytes = 4 * eW * 2;             // 4.72 MB

    auto needBytes = [&](long long cb, long long sc) {
        const long long s = 8 * perP * sc;           // Sf f32 bytes
        const long long x = 4 * perB * cb;           // xABb bf16 bytes
        return (s > x ? s : x) + 10 * perB * cb;     // + Qb + KbACC + Vtb
    };

    int CbFit = 1;
    for (int c = BATCH; c >= 1; --c) {
        const long long sc = c < 8 ? c : 8;
        if (wBytes + needBytes(c, sc) <= (long long)ws_size) { CbFit = c; break; }
    }
    const int nChunks = (BATCH + CbFit - 1) / CbFit;
    const int CbStd   = (BATCH + nChunks - 1) / nChunks;

    char* cur = (char*)d_ws;
    ushort_t* Wqb  = (ushort_t*)cur; cur += eW * 2;
    ushort_t* Wkvb = (ushort_t*)cur; cur += 2 * eW * 2;    // [Wk; Wv] 1536x768
    ushort_t* Wfcb = (ushort_t*)cur; cur += eW * 2;
    char* chunkBase = cur;

    const float scale = 0.03608439182435161f;  // 1/sqrt(768)

    f32_to_bf16<<<(int)(eW / 1024), 256, 0, stream>>>(Wq,  Wqb);
    f32_to_bf16<<<(int)(eW / 1024), 256, 0, stream>>>(Wk,  Wkvb);
    f32_to_bf16<<<(int)(eW / 1024), 256, 0, stream>>>(Wv,  Wkvb + eW);
    f32_to_bf16<<<(int)(eW / 1024), 256, 0, stream>>>(Wfc, Wfcb);

    for (int b0 = 0; b0 < BATCH; b0 += CbStd) {
        const int Cb = (b0 + CbStd <= BATCH) ? CbStd : (BATCH - b0);
        const long long off = (long long)b0 * perB;

        int SC = Cb;
        while (SC > 1 && wBytes + needBytes(Cb, SC) > (long long)ws_size) --SC;

        const long long Sbytes =
            (8 * perP * (long long)SC > 4 * perB * (long long)Cb)
                ? 8 * perP * (long long)SC : 4 * perB * (long long)Cb;

        char* p = chunkBase;
        ushort_t* xCb  = (ushort_t*)p;                 // overlay 1 in region S
        ushort_t* xABb = (ushort_t*)p;                 // overlay 2 in region S
        float*    Sf   = (float*)p;    p += Sbytes;    // overlay 3 in region S
        ushort_t* Qb   = (ushort_t*)p; p += 2 * perB * Cb;
        ushort_t* Kb   = (ushort_t*)p;
        float*    ACC  = (float*)p;    p += 4 * perB * Cb;   // ACC overlays Kb
        ushort_t* Vtb  = (ushort_t*)p; p += 4 * perB * Cb;

        dim3 gq  (DIMV / 256, Cb * (SEQ / 256), 1);           // (3, 64)
        dim3 gkv (2 * DIMV / 256, 2 * Cb * (SEQ / 256), 1);   // (6, 128)
        const int gcv = (int)((long long)Cb * perB / 1024);

        // 1) projections: Q from xC; fused K|V GEMM from stacked xA|xB
        f32_to_bf16<<<gcv, 256, 0, stream>>>(xC + off, xCb);
        gemm_bf16_nt_256<<<gq, 512, 0, stream>>>(xCb, Wqb, bq, nullptr, Qb, nullptr,
            DIMV, DIMV, DIMV, DIMV, 1.f, 1, 0, 0, 0, 0);
        f32_to_bf16<<<gcv, 256, 0, stream>>>(xA + off, xABb);
        f32_to_bf16<<<gcv, 256, 0, stream>>>(xB + off, xABb + (long long)Cb * perB);
        gemm_bf16_nt_256<<<gkv, 512, 0, stream>>>(xABb, Wkvb, bk, bv, Kb, Vtb,
            DIMV, DIMV, DIMV, DIMV, 1.f, 4, 0, 0, 0, Cb);

        // 2) branch-fused attention, SC batches per sub-pass
        for (int s0 = 0; s0 < Cb; s0 += SC) {
            const int sc = (s0 + SC <= Cb) ? SC : (Cb - s0);
            dim3 gsc(2 * SEQ / 256, SEQ / 256, sc);           // (8, 4, sc)
            dim3 gpv(DIMV / 128, SEQ / 128, sc);              // 128^2 kernel

            gemm_bf16_nt_256<<<gsc, 512, 0, stream>>>(
                Qb + (long long)s0 * perB, Kb + (long long)s0 * 2 * perB,
                nullptr, nullptr, Sf, nullptr,
                DIMV, DIMV, DIMV, 2 * SEQ, scale, 0, perB, 2 * perB, 2 * perP, 0);

            softmax2_inplace<<<sc * SEQ, 256, 0, stream>>>(Sf);

            gemm_bf16_nt<<<gpv, 256, 0, stream>>>(
                (const ushort_t*)Sf, Vtb + (long long)s0 * 2 * perB,
                nullptr, ACC + (long long)s0 * perB,
                2 * SEQ, 4 * SEQ, 2 * SEQ, DIMV, 1.f, 4 * perP, 2 * perB, perB);
        }

        // 3) h = LN(ACC + xC) -> bf16, into Qb (Q is dead now)
        add_layernorm<<<Cb * SEQ, 256, 0, stream>>>(ACC, xC + off, gamma, beta, Qb);

        // 4) out = h @ Wfc^T + bfc (f32 out)
        gemm_bf16_nt_256<<<gq, 512, 0, stream>>>(Qb, Wfcb, bfc, nullptr, out + off, nullptr,
            DIMV, DIMV, DIMV, DIMV, 1.f, 0, 0, 0, 0, 0);
    }
}

// Round 11
// 621.705 us; speedup vs baseline: 3.6520x; 3.6520x over previous
//
#include <hip/hip_runtime.h>

#define DIMV 768
#define BATCH 16
#define SEQ 1024
#define LN_EPS 1e-5f

typedef __attribute__((ext_vector_type(8))) short bf16x8;   // 8 bf16 = 4 VGPRs
typedef __attribute__((ext_vector_type(4))) float f32x4;
typedef unsigned short ushort_t;

__device__ __forceinline__ unsigned short f2bf(float f) {
    unsigned u = __float_as_uint(f);
    u = (u + 0x7FFFu + ((u >> 16) & 1u)) >> 16;
    return (unsigned short)u;
}

// ---------------------------------------------------------------------------
// Verified building blocks (rounds 0-10):
//  - LDS chunk swizzle on global SOURCE + frag-read XOR (conflicts -> 0).
//  - XCD swizzles: Z>1 -> XCD == batch (mod 8); Z==1 -> chunked y-range.
//  - Branch-fused attention; lifetime overlays -> single chunk Cb=16.
// GEMM structure ledger (pre-committed A/B outcomes, all ~466-480 TF):
//  r4 depth-2@128^2 REFUTED (occupancy), r6 256^2@1blk +6.6%, r7 depth-2
//  iso-occ NULL, r8 BK=64 ring-2 NULL, r9 8-phase NULL,
//  r10 256^2@2blk INFEASIBLE: __launch_bounds__ min-waves=4 forced VGPR=64,
//  acc[8][4] spilled to scratch (WRITE 2.4 GB, MfmaUtil 3%, 6x slower).
//  NEVER use the min-waves arg to force occupancy past register demand.
// THIS ROUND: revert to r7 best + grid-fill fix: Q/fc at 256^2 had
//  192 blocks = 0.75 blk/CU (quarter of chip idle, no TLP at 256^2).
//  128^2 gives 768 blocks = 3/CU full fill + measured 3-block TLP.
//  Assignment: KV(768blk full-fill 3 passes) + score(256blk = 1.00/CU)
//  stay 256^2; Q/fc/PV run 128^2.
// ---------------------------------------------------------------------------

// ---------------------------------------------------------------------------
// 256x256 tile GEMM: 512 threads = 8 waves (2 m-halves x 4 n-quarters),
// per-wave 128x64 output = acc[8][4] f32x4. BK=32, ring-4 LDS (128 KB),
// depth-2 prefetch, counted vmcnt(8), setprio around MFMA cluster.
// [r7 configuration — best measured total]
// Ring-4 safety: slot (k+2)&3 was last read at iter k-2; those reads precede
// that wave's barrier(k-1); the iter-k issue follows barrier(k-1). Tail
// iters issue clamped dummy loads (last tile, L2-hot, never read).
// mode: 0 = f32 out; 1 = bf16 out; 4 = fused KV epilogue (branch-stacked):
//           bh = m>>10, half = bh>=CbArg, b = bh - half*CbArg
//           n < 768 : K  -> Cout [b][half*1024 + s][n]       (bf16)
//           n >= 768: V^T-> Cout2[b][n-768][half*1024 + s]   (bf16)
// ---------------------------------------------------------------------------
__global__ __launch_bounds__(512, 2) void gemm_bf16_nt_256(
    const ushort_t* __restrict__ A, const ushort_t* __restrict__ B,
    const float* __restrict__ bias, const float* __restrict__ bias2,
    void* __restrict__ Cout, void* __restrict__ Cout2,
    int K, int lda, int ldb, int ldc, float scale, int mode,
    long long sAz, long long sBz, long long sCz, int CbArg)
{
    int bx = blockIdx.x, by = blockIdx.y, bz = blockIdx.z;
    {
        const unsigned Z  = gridDim.z;
        const unsigned nx = gridDim.x, ny = gridDim.y;
        if (Z > 1) {
            const unsigned nxy = nx * ny;
            const unsigned lid = ((unsigned)bz * ny + (unsigned)by) * nx + (unsigned)bx;
            unsigned r;
            if ((Z & 7u) == 0u) {
                const unsigned c  = lid & 7u;
                const unsigned rp = lid >> 3;
                bz = (int)(c + 8u * (rp / nxy));
                r  = rp % nxy;
            } else {
                bz = (int)(lid % Z);
                r  = lid / Z;
            }
            bx = (int)(r % nx);
            by = (int)(r / nx);
        } else {
            const unsigned nwg = nx * ny;
            if ((nwg & 7u) == 0u) {
                const unsigned lid = (unsigned)by * nx + (unsigned)bx;
                const unsigned nl  = (lid & 7u) * (nwg >> 3) + (lid >> 3);
                bx = (int)(nl % nx);
                by = (int)(nl / nx);
            }
        }
    }

    A += (long long)bz * sAz;
    B += (long long)bz * sBz;
    float*    Cf  = (float*)Cout    + ((mode == 0) ? (long long)bz * sCz : 0);
    ushort_t* Ch  = (ushort_t*)Cout + ((mode == 1) ? (long long)bz * sCz : 0);
    ushort_t* Ch2 = (ushort_t*)Cout2;

    __shared__ ushort_t As[4][256 * 32];   // 4 x 16 KB
    __shared__ ushort_t Bs[4][256 * 32];   // 4 x 16 KB  (128 KB total)

    const int t    = threadIdx.x;       // 0..511
    const int wave = t >> 6;            // 0..7
    const int lane = t & 63;
    const int quad = lane >> 4;         // 0..3
    const int lr   = lane & 15;         // 0..15
    const int wy   = wave >> 2;         // 0/1: m-half (128 rows)
    const int wx   = wave & 3;          // 0..3: n-quarter (64 cols)

    const int m0 = by * 256;
    const int n0 = bx * 256;

    const ushort_t* Abase = A + (long long)m0 * lda;
    const ushort_t* Bbase = B + (long long)n0 * ldb;

    auto issue = [&](int k0, int slot) {
        #pragma unroll
        for (int i = 0; i < 2; ++i) {
            const int idx = t + 512 * i;          // 0..1023: 256 rows x 4 chunks
            const int r   = idx >> 2;
            const int q   = idx & 3;              // LDS chunk slot
            const int c   = (q ^ ((r >> 1) & 3)) * 8;  // swizzled global chunk
            __builtin_amdgcn_global_load_lds(
                (const __attribute__((address_space(1))) unsigned int*)(Abase + (long long)r * lda + k0 + c),
                (__attribute__((address_space(3))) unsigned int*)&As[slot][idx * 8], 16, 0, 0);
            __builtin_amdgcn_global_load_lds(
                (const __attribute__((address_space(1))) unsigned int*)(Bbase + (long long)r * ldb + k0 + c),
                (__attribute__((address_space(3))) unsigned int*)&Bs[slot][idx * 8], 16, 0, 0);
        }
    };

    int offA[8], offB[4];
    #pragma unroll
    for (int i = 0; i < 8; ++i) {
        const int rowA = wy * 128 + i * 16 + lr;
        offA[i] = rowA * 32 + ((quad ^ ((rowA >> 1) & 3)) * 8);
    }
    #pragma unroll
    for (int j = 0; j < 4; ++j) {
        const int rowB = wx * 64 + j * 16 + lr;
        offB[j] = rowB * 32 + ((quad ^ ((rowB >> 1) & 3)) * 8);
    }

    f32x4 acc[8][4] = {};

    const int NK = K >> 5;                 // >= 24 for all callers
    issue(0, 0);
    issue(32, 1);
    for (int ki = 0; ki < NK; ++ki) {
        const int k2 = (ki + 2 < NK) ? (ki + 2) << 5 : (NK - 1) << 5;  // clamped dummy
        issue(k2, (ki + 2) & 3);
        asm volatile("s_waitcnt vmcnt(8)" ::: "memory");   // tile-k done; k+1,k+2 in flight
        asm volatile("s_barrier" ::: "memory");            // no vmcnt(0) drain

        const ushort_t* as = &As[ki & 3][0];
        const ushort_t* bs = &Bs[ki & 3][0];
        bf16x8 af[8], bfr[4];
        #pragma unroll
        for (int i = 0; i < 8; ++i) af[i]  = *(const bf16x8*)&as[offA[i]];
        #pragma unroll
        for (int j = 0; j < 4; ++j) bfr[j] = *(const bf16x8*)&bs[offB[j]];

        __builtin_amdgcn_s_setprio(1);
        #pragma unroll
        for (int i = 0; i < 8; ++i)
            #pragma unroll
            for (int j = 0; j < 4; ++j)
                acc[i][j] = __builtin_amdgcn_mfma_f32_16x16x32_bf16(
                    af[i], bfr[j], acc[i][j], 0, 0, 0);
        __builtin_amdgcn_s_setprio(0);
    }

    // epilogue: D row(m) = quad*4 + reg, col(n) = lane&15  [m89-verified]
    #pragma unroll
    for (int j = 0; j < 4; ++j) {
        const int n = n0 + wx * 64 + j * 16 + lr;
        float bv;
        if (mode == 4) bv = (n < DIMV) ? bias[n] : bias2[n - DIMV];
        else           bv = bias ? bias[n] : 0.0f;
        #pragma unroll
        for (int i = 0; i < 8; ++i) {
            #pragma unroll
            for (int r = 0; r < 4; ++r) {
                const int m = m0 + wy * 128 + i * 16 + quad * 4 + r;
                const float val = acc[i][j][r] * scale + bv;
                if (mode == 0) {
                    Cf[(long long)m * ldc + n] = val;
                } else if (mode == 1) {
                    Ch[(long long)m * ldc + n] = f2bf(val);
                } else {                      // mode 4: fused KV, branch-stacked
                    const int bh = m >> 10, s = m & 1023;
                    const int hf = (bh >= CbArg) ? 1 : 0;
                    const int b  = bh - (hf ? CbArg : 0);
                    if (n < DIMV) {
                        Ch[(long long)b * (2 * SEQ * DIMV) + (long long)(hf * SEQ + s) * DIMV + n] = f2bf(val);
                    } else {
                        Ch2[(long long)b * (2 * SEQ * DIMV) + (long long)(n - DIMV) * (2 * SEQ) + hf * SEQ + s] = f2bf(val);
                    }
                }
            }
        }
    }
}

// ---------------------------------------------------------------------------
// 128x128 tile GEMM, BK=32 ring-3 depth-1 (verified rounds 0-5): 3 blocks/CU
// TLP. Used for PV (K=2048) and for Q/fc (grid 768 blocks = 3/CU full fill;
// at 256^2 these shapes gave only 192 blocks = 0.75/CU).
// mode: 0 = f32 out; 1 = bf16 out.
// ---------------------------------------------------------------------------
__global__ __launch_bounds__(256) void gemm_bf16_nt(
    const ushort_t* __restrict__ A, const ushort_t* __restrict__ B,
    const float* __restrict__ bias, void* __restrict__ Cout,
    int K, int lda, int ldb, int ldc, float scale, int mode,
    long long sAz, long long sBz, long long sCz)
{
    int bx = blockIdx.x, by = blockIdx.y, bz = blockIdx.z;
    {
        const unsigned Z  = gridDim.z;
        const unsigned nx = gridDim.x, ny = gridDim.y;
        if (Z > 1) {
            const unsigned nxy = nx * ny;
            const unsigned lid = ((unsigned)bz * ny + (unsigned)by) * nx + (unsigned)bx;
            unsigned r;
            if ((Z & 7u) == 0u) {
                const unsigned c  = lid & 7u;
                const unsigned rp = lid >> 3;
                bz = (int)(c + 8u * (rp / nxy));
                r  = rp % nxy;
            } else {
                bz = (int)(lid % Z);
                r  = lid / Z;
            }
            bx = (int)(r % nx);
            by = (int)(r / nx);
        } else {
            const unsigned nwg = nx * ny;
            if ((nwg & 7u) == 0u) {
                const unsigned lid = (unsigned)by * nx + (unsigned)bx;
                const unsigned nl  = (lid & 7u) * (nwg >> 3) + (lid >> 3);
                bx = (int)(nl % nx);
                by = (int)(nl / nx);
            }
        }
    }

    A += (long long)bz * sAz;
    B += (long long)bz * sBz;
    float*    Cf = (float*)Cout    + ((mode == 0) ? (long long)bz * sCz : 0);
    ushort_t* Ch = (ushort_t*)Cout + ((mode == 1) ? (long long)bz * sCz : 0);

    __shared__ ushort_t As[3][128 * 32];
    __shared__ ushort_t Bs[3][128 * 32];

    const int t    = threadIdx.x;
    const int wave = t >> 6;
    const int lane = t & 63;
    const int quad = lane >> 4;
    const int lr   = lane & 15;
    const int wy   = wave >> 1;
    const int wx   = wave & 1;

    const int m0 = by * 128;
    const int n0 = bx * 128;

    const ushort_t* Abase = A + (long long)m0 * lda;
    const ushort_t* Bbase = B + (long long)n0 * ldb;

    auto issue = [&](int k0, int slot) {
        #pragma unroll
        for (int i = 0; i < 2; ++i) {
            const int idx = t + 256 * i;
            const int r   = idx >> 2;
            const int q   = idx & 3;
            const int c   = (q ^ ((r >> 1) & 3)) * 8;
            __builtin_amdgcn_global_load_lds(
                (const __attribute__((address_space(1))) unsigned int*)(Abase + (long long)r * lda + k0 + c),
                (__attribute__((address_space(3))) unsigned int*)&As[slot][idx * 8], 16, 0, 0);
            __builtin_amdgcn_global_load_lds(
                (const __attribute__((address_space(1))) unsigned int*)(Bbase + (long long)r * ldb + k0 + c),
                (__attribute__((address_space(3))) unsigned int*)&Bs[slot][idx * 8], 16, 0, 0);
        }
    };

    int offA[4], offB[4];
    #pragma unroll
    for (int i = 0; i < 4; ++i) {
        const int rowA = wy * 64 + i * 16 + lr;
        offA[i] = rowA * 32 + ((quad ^ ((rowA >> 1) & 3)) * 8);
        const int rowB = wx * 64 + i * 16 + lr;
        offB[i] = rowB * 32 + ((quad ^ ((rowB >> 1) & 3)) * 8);
    }

    f32x4 acc[4][4] = {};

    const int NK = K >> 5;
    issue(0, 0);
    int cur = 0, nxt = 1;
    for (int ki = 0; ki < NK; ++ki) {
        const int kn = (ki + 1 < NK) ? (ki + 1) << 5 : 0;
        issue(kn, nxt);
        asm volatile("s_waitcnt vmcnt(4)" ::: "memory");
        asm volatile("s_barrier" ::: "memory");

        const ushort_t* as = &As[cur][0];
        const ushort_t* bs = &Bs[cur][0];
        bf16x8 af[4], bfr[4];
        #pragma unroll
        for (int i = 0; i < 4; ++i) af[i]  = *(const bf16x8*)&as[offA[i]];
        #pragma unroll
        for (int j = 0; j < 4; ++j) bfr[j] = *(const bf16x8*)&bs[offB[j]];

        #pragma unroll
        for (int i = 0; i < 4; ++i)
            #pragma unroll
            for (int j = 0; j < 4; ++j)
                acc[i][j] = __builtin_amdgcn_mfma_f32_16x16x32_bf16(
                    af[i], bfr[j], acc[i][j], 0, 0, 0);

        cur = nxt;
        nxt = (nxt == 2) ? 0 : nxt + 1;
    }

    #pragma unroll
    for (int j = 0; j < 4; ++j) {
        const int n = n0 + wx * 64 + j * 16 + lr;
        const float bv = bias ? bias[n] : 0.0f;
        #pragma unroll
        for (int i = 0; i < 4; ++i) {
            #pragma unroll
            for (int r = 0; r < 4; ++r) {
                const int m = m0 + wy * 64 + i * 16 + quad * 4 + r;
                const float val = acc[i][j][r] * scale + bv;
                if (mode == 0) Cf[(long long)m * ldc + n] = val;
                else           Ch[(long long)m * ldc + n] = f2bf(val);
            }
        }
    }
}

// ---------------------------------------------------------------------------
// f32 -> bf16 conversion, 4 elems/thread, count divisible by 1024
// ---------------------------------------------------------------------------
__global__ __launch_bounds__(256) void f32_to_bf16(
    const float* __restrict__ in, ushort_t* __restrict__ out)
{
    const long long i = ((long long)blockIdx.x * 256 + threadIdx.x) * 4;
    float4 v = *reinterpret_cast<const float4*>(in + i);
    ushort4 o;
    o.x = f2bf(v.x); o.y = f2bf(v.y); o.z = f2bf(v.z); o.w = f2bf(v.w);
    *reinterpret_cast<ushort4*>(out + i) = o;
}

// Dual-source variant: elems [0,half) from inA, [half,2*half) from inB.
// One dispatch replaces the xA+xB conversion pair (one less launch tail).
__global__ __launch_bounds__(256) void f32_to_bf16_2(
    const float* __restrict__ inA, const float* __restrict__ inB,
    ushort_t* __restrict__ out, long long half)
{
    const long long i = ((long long)blockIdx.x * 256 + threadIdx.x) * 4;
    const float* src = (i < half) ? (inA + i) : (inB + (i - half));
    float4 v = *reinterpret_cast<const float4*>(src);
    ushort4 o;
    o.x = f2bf(v.x); o.y = f2bf(v.y); o.z = f2bf(v.z); o.w = f2bf(v.w);
    *reinterpret_cast<ushort4*>(out + i) = o;
}

// ---------------------------------------------------------------------------
// Dual in-place row softmax over a [2048] f32 row (two independent 1024
// halves). Row overwritten with 2048 contiguous bf16 probs. [verified r4]
// ---------------------------------------------------------------------------
__global__ __launch_bounds__(256) void softmax2_inplace(float* __restrict__ S)
{
    float* s = S + (long long)blockIdx.x * (2 * SEQ);
    const int t  = threadIdx.x;
    const int hf = t >> 7;
    const int tt = t & 127;
    const int base = hf * SEQ + tt * 8;
    __shared__ float red[256];

    float4 v0 = *reinterpret_cast<const float4*>(&s[base]);
    float4 v1 = *reinterpret_cast<const float4*>(&s[base + 4]);
    float mx = fmaxf(fmaxf(fmaxf(v0.x, v0.y), fmaxf(v0.z, v0.w)),
                     fmaxf(fmaxf(v1.x, v1.y), fmaxf(v1.z, v1.w)));
    red[t] = mx;
    __syncthreads();
    for (int st = 64; st > 0; st >>= 1) {
        if (tt < st) red[t] = fmaxf(red[t], red[t + st]);
        __syncthreads();
    }
    mx = red[hf << 7];
    __syncthreads();

    v0.x = __expf(v0.x - mx); v0.y = __expf(v0.y - mx);
    v0.z = __expf(v0.z - mx); v0.w = __expf(v0.w - mx);
    v1.x = __expf(v1.x - mx); v1.y = __expf(v1.y - mx);
    v1.z = __expf(v1.z - mx); v1.w = __expf(v1.w - mx);
    red[t] = (v0.x + v0.y + v0.z + v0.w) + (v1.x + v1.y + v1.z + v1.w);
    __syncthreads();
    for (int st = 64; st > 0; st >>= 1) {
        if (tt < st) red[t] += red[t + st];
        __syncthreads();
    }
    const float inv = 1.0f / red[hf << 7];

    ushort4 o0, o1;
    o0.x = f2bf(v0.x * inv); o0.y = f2bf(v0.y * inv);
    o0.z = f2bf(v0.z * inv); o0.w = f2bf(v0.w * inv);
    o1.x = f2bf(v1.x * inv); o1.y = f2bf(v1.y * inv);
    o1.z = f2bf(v1.z * inv); o1.w = f2bf(v1.w * inv);
    *reinterpret_cast<ushort4*>((ushort_t*)s + base)     = o0;
    *reinterpret_cast<ushort4*>((ushort_t*)s + base + 4) = o1;
}

// ---------------------------------------------------------------------------
// h = LayerNorm(ACC + xC) * gamma + beta -> bf16. One block per row (768).
// ---------------------------------------------------------------------------
__global__ __launch_bounds__(256) void add_layernorm(
    const float* __restrict__ ACC, const float* __restrict__ xC,
    const float* __restrict__ gamma, const float* __restrict__ beta,
    ushort_t* __restrict__ H)
{
    const long long row = blockIdx.x;
    const float* a = ACC + row * DIMV;
    const float* x = xC  + row * DIMV;
    ushort_t*    h = H   + row * DIMV;
    const int t = threadIdx.x;

    __shared__ float r1[256];
    __shared__ float r2[256];

    float vals[3];
    float s = 0.f, ss = 0.f;
    #pragma unroll
    for (int i = 0; i < 3; ++i) {
        const int j = t + i * 256;
        float v = a[j] + x[j];
        vals[i] = v;
        s += v; ss += v * v;
    }
    r1[t] = s; r2[t] = ss;
    __syncthreads();
    for (int st = 128; st > 0; st >>= 1) {
        if (t < st) { r1[t] += r1[t + st]; r2[t] += r2[t + st]; }
        __syncthreads();
    }
    const float mu  = r1[0] * (1.0f / DIMV);
    const float var = r2[0] * (1.0f / DIMV) - mu * mu;
    const float inv = rsqrtf(var + LN_EPS);

    #pragma unroll
    for (int i = 0; i < 3; ++i) {
        const int j = t + i * 256;
        h[j] = f2bf((vals[i] - mu) * inv * gamma[j] + beta[j]);
    }
}

// ---------------------------------------------------------------------------
// Launch. Persistent: bf16 weights Wqb | Wkvb (=[Wk;Wv]) | Wfcb (4.72 MB).
// Lifetime-overlay layout per chunk [verified round 5, single chunk Cb=16]:
//   Region S: xCb / xABb / Sf (sequential lifetimes)
//   Qb; KbACC (Kb overlaid by ACC per sub-pass); Vtb
// Attention branch-fused per SC-batch sub-pass:
//   score (N=2048) -> dual softmax -> PV (K=2048, no RMW).
// Kernel assignment by grid fill: KV + score -> 256^2 (full fill);
// Q / fc / PV -> 128^2 (768-blk grids, 3 blocks/CU TLP).
// ---------------------------------------------------------------------------
extern "C" void kernel_launch(void* const* d_in, const int* in_sizes, int n_in,
                              void* d_out, int out_size, void* d_ws, size_t ws_size,
                              hipStream_t stream)
{
    const float* xA    = (const float*)d_in[0];
    const float* xB    = (const float*)d_in[1];
    const float* xC    = (const float*)d_in[2];
    const float* Wq    = (const float*)d_in[3];
    const float* bq    = (const float*)d_in[4];
    const float* Wk    = (const float*)d_in[5];
    const float* bk    = (const float*)d_in[6];
    const float* Wv    = (const float*)d_in[7];
    const float* bv    = (const float*)d_in[8];
    const float* gamma = (const float*)d_in[9];
    const float* beta  = (const float*)d_in[10];
    const float* Wfc   = (const float*)d_in[11];
    const float* bfc   = (const float*)d_in[12];
    float* out = (float*)d_out;

    const long long eW   = (long long)DIMV * DIMV;   // 589,824
    const long long perB = (long long)SEQ * DIMV;    // 786,432 elems
    const long long perP = (long long)SEQ * SEQ;     // 1,048,576 elems

    const long long wBytes = 4 * eW * 2;             // 4.72 MB

    auto needBytes = [&](long long cb, long long sc) {
        const long long s = 8 * perP * sc;           // Sf f32 bytes
        const long long x = 4 * perB * cb;           // xABb bf16 bytes
        return (s > x ? s : x) + 10 * perB * cb;     // + Qb + KbACC + Vtb
    };

    int CbFit = 1;
    for (int c = BATCH; c >= 1; --c) {
        const long long sc = c < 8 ? c : 8;
        if (wBytes + needBytes(c, sc) <= (long long)ws_size) { CbFit = c; break; }
    }
    const int nChunks = (BATCH + CbFit - 1) / CbFit;
    const int CbStd   = (BATCH + nChunks - 1) / nChunks;

    char* cur = (char*)d_ws;
    ushort_t* Wqb  = (ushort_t*)cur; cur += eW * 2;
    ushort_t* Wkvb = (ushort_t*)cur; cur += 2 * eW * 2;    // [Wk; Wv] 1536x768
    ushort_t* Wfcb = (ushort_t*)cur; cur += eW * 2;
    char* chunkBase = cur;

    const float scale = 0.03608439182435161f;  // 1/sqrt(768)

    f32_to_bf16<<<(int)(eW / 1024), 256, 0, stream>>>(Wq,  Wqb);
    f32_to_bf16<<<(int)(eW / 1024), 256, 0, stream>>>(Wk,  Wkvb);
    f32_to_bf16<<<(int)(eW / 1024), 256, 0, stream>>>(Wv,  Wkvb + eW);
    f32_to_bf16<<<(int)(eW / 1024), 256, 0, stream>>>(Wfc, Wfcb);

    for (int b0 = 0; b0 < BATCH; b0 += CbStd) {
        const int Cb = (b0 + CbStd <= BATCH) ? CbStd : (BATCH - b0);
        const long long off = (long long)b0 * perB;

        int SC = Cb;
        while (SC > 1 && wBytes + needBytes(Cb, SC) > (long long)ws_size) --SC;

        const long long Sbytes =
            (8 * perP * (long long)SC > 4 * perB * (long long)Cb)
                ? 8 * perP * (long long)SC : 4 * perB * (long long)Cb;

        char* p = chunkBase;
        ushort_t* xCb  = (ushort_t*)p;                 // overlay 1 in region S
        ushort_t* xABb = (ushort_t*)p;                 // overlay 2 in region S
        float*    Sf   = (float*)p;    p += Sbytes;    // overlay 3 in region S
        ushort_t* Qb   = (ushort_t*)p; p += 2 * perB * Cb;
        ushort_t* Kb   = (ushort_t*)p;
        float*    ACC  = (float*)p;    p += 4 * perB * Cb;   // ACC overlays Kb
        ushort_t* Vtb  = (ushort_t*)p; p += 4 * perB * Cb;

        dim3 gq128(DIMV / 128, Cb * (SEQ / 128), 1);          // (6, 128) = 768 blk
        dim3 gkv  (2 * DIMV / 256, 2 * Cb * (SEQ / 256), 1);  // (6, 128) = 768 blk
        const int gcv = (int)((long long)Cb * perB / 1024);

        // 1) projections: Q from xC (128^2, full fill); fused K|V (256^2)
        f32_to_bf16<<<gcv, 256, 0, stream>>>(xC + off, xCb);
        gemm_bf16_nt<<<gq128, 256, 0, stream>>>(xCb, Wqb, bq, Qb,
            DIMV, DIMV, DIMV, DIMV, 1.f, 1, 0, 0, 0);
        f32_to_bf16_2<<<2 * gcv, 256, 0, stream>>>(xA + off, xB + off, xABb,
            (long long)Cb * perB);
        gemm_bf16_nt_256<<<gkv, 512, 0, stream>>>(xABb, Wkvb, bk, bv, Kb, Vtb,
            DIMV, DIMV, DIMV, DIMV, 1.f, 4, 0, 0, 0, Cb);

        // 2) branch-fused attention, SC batches per sub-pass
        for (int s0 = 0; s0 < Cb; s0 += SC) {
            const int sc = (s0 + SC <= Cb) ? SC : (Cb - s0);
            dim3 gsc(2 * SEQ / 256, SEQ / 256, sc);           // 256^2: (8,4,sc)
            dim3 gpv(DIMV / 128, SEQ / 128, sc);              // 128^2: (6,8,sc)

            gemm_bf16_nt_256<<<gsc, 512, 0, stream>>>(
                Qb + (long long)s0 * perB, Kb + (long long)s0 * 2 * perB,
                nullptr, nullptr, Sf, nullptr,
                DIMV, DIMV, DIMV, 2 * SEQ, scale, 0, perB, 2 * perB, 2 * perP, 0);

            softmax2_inplace<<<sc * SEQ, 256, 0, stream>>>(Sf);

            gemm_bf16_nt<<<gpv, 256, 0, stream>>>(
                (const ushort_t*)Sf, Vtb + (long long)s0 * 2 * perB,
                nullptr, ACC + (long long)s0 * perB,
                2 * SEQ, 4 * SEQ, 2 * SEQ, DIMV, 1.f, 0, 4 * perP, 2 * perB, perB);
        }

        // 3) h = LN(ACC + xC) -> bf16, into Qb (Q is dead now)
        add_layernorm<<<Cb * SEQ, 256, 0, stream>>>(ACC, xC + off, gamma, beta, Qb);

        // 4) out = h @ Wfc^T + bfc (f32 out, 128^2 full fill)
        gemm_bf16_nt<<<gq128, 256, 0, stream>>>(Qb, Wfcb, bfc, out + off,
            DIMV, DIMV, DIMV, DIMV, 1.f, 0, 0, 0, 0);
    }
}